// Round 1
// 637.517 us; speedup vs baseline: 1.0423x; 1.0423x over previous
//
#include <hip/hip_runtime.h>

#define N_    64
#define CIN_  192
#define T_    256
#define V_    25
#define K_    3
#define COUT_ 64
#define OC_   192
#define SS_   5

#define OUT_OFF_A (N_*COUT_*T_*V_)          // 26214400
#define OUT_OFF_G (OUT_OFF_A + K_*V_*V_)    // 26216275

#define TCH   4              // t's per inner chunk
#define HCH   4              // chunks per block -> 16 t's per block
#define NCOLS 100            // TCH*V_
#define XB_STRIDE 200        // shorts per XB row (192 + 8 pad); 400B = 25*16B (aligned)
#define YB_STRIDE 104        // shorts per YB row (75 -> pad 96 -> 104)
#define UNION_SHORTS 26624   // max(112*200, 256*104)  -> 53248 B : 3 blocks/CU
#define NYV  4800            // OC_*V_ : per-n ybar size
#define CPN  (T_/(TCH*HCH))  // 16 chunk-blocks per n
#define NBLK (N_*CPN)        // 1024 fused blocks
#define CHUNK_UNITS ((CIN_/8)*NCOLS)   // 2400 b128 staging units per chunk

typedef __attribute__((ext_vector_type(8))) short short8;
typedef __attribute__((ext_vector_type(4))) float float4v;

__device__ inline unsigned bf16r(float f) {            // fp32 -> bf16 RNE
    unsigned u = __float_as_uint(f);
    return (u + 0x7fffu + ((u >> 16) & 1u)) >> 16;
}

// ---------- prep: WcB (bf16), A2T (Acat^T, bf16, zero-padded), A passthrough ----
__global__ __launch_bounds__(256) void prep(const float* __restrict__ Wc,
                                            const float* __restrict__ A,
                                            short* __restrict__ WcB,
                                            short* __restrict__ A2T,
                                            float* __restrict__ out) {
    int idx = blockIdx.x * 256 + threadIdx.x;
    if (idx < OC_ * CIN_) WcB[idx] = (short)bf16r(Wc[idx]);
    if (idx < 32 * YB_STRIDE) {           // A2T[w][kk], kk = k*25+v, zeros elsewhere
        int w = idx / YB_STRIDE, kk = idx - w * YB_STRIDE;
        short val = 0;
        if (w < V_ && kk < K_ * V_) {
            int k = kk / V_, v = kk - k * V_;
            val = (short)bf16r(A[k * V_ * V_ + v * V_ + w]);
        }
        A2T[idx] = val;
    }
    if (idx < K_ * V_ * V_) out[OUT_OFF_A + idx] = A[idx];
}

// ---------- fused MFMA: y = Wc@x+bc, out = Ycat@Acat, + per-block y t-partials --
// Zero-fill phase removed: A2T pad columns (k in [75,96)) are exact zeros, so any
// FINITE stale bf16 in YB's pad columns contributes exactly 0. One-time zero of U
// at entry guarantees no NaN/Inf bit patterns; all later writes are finite bf16.
__global__ __launch_bounds__(256, 2) void fused_mfma(const float* __restrict__ x,
                                                     const short* __restrict__ WcB,
                                                     const float* __restrict__ bc,
                                                     const short* __restrict__ A2T,
                                                     float* __restrict__ out,
                                                     float* __restrict__ part) {
    __shared__ __align__(16) short U[UNION_SHORTS];   // XB then YB, per chunk

    const int tid  = threadIdx.x;
    const int lane = tid & 63;
    const int wv   = tid >> 6;
    const int l15  = lane & 15;
    const int q    = lane >> 4;
    const int n    = blockIdx.x >> 4;
    const int tc   = blockIdx.x & 15;

    // one-time zero: every byte of U is finite forever after
    {
        int4 z = make_int4(0, 0, 0, 0);
        for (int i = tid; i < UNION_SHORTS / 8; i += 256) ((int4*)U)[i] = z;
    }

    // Wc A-fragments resident in registers: wave wv owns rows [wv*48, wv*48+48)
    short8 wfrag[3][6];
    const int rt0 = wv * 3;
    {
        const short* wb = WcB + (rt0 * 16 + l15) * CIN_ + q * 8;
#pragma unroll
        for (int j = 0; j < 3; ++j)
#pragma unroll
            for (int ks = 0; ks < 6; ++ks)
                wfrag[j][ks] = *(const short8*)(wb + j * 16 * CIN_ + ks * 32);
    }

    float racc[19];
#pragma unroll
    for (int u = 0; u < 19; ++u) racc[u] = 0.f;

    for (int h = 0; h < HCH; ++h) {
        const int t0 = tc * (TCH * HCH) + h * TCH;
        __syncthreads();   // previous chunk done with U (also orders the init zero)

        // stage XB[col][c] (bf16, transposed) — conflict-free:
        // each thread loads 8 strided floats (coalesced across lanes) and emits
        // ONE aligned ds_write_b128 instead of 4 scattered short writes.
        const float* xn = x + (size_t)n * (CIN_ * T_ * V_) + t0 * V_;
        for (int u = tid; u < CHUNK_UNITS; u += 256) {
            int col = u % NCOLS;
            int cg  = u / NCOLS;
            const float* xp = xn + (size_t)cg * 8 * (T_ * V_) + col;
            short8 s;
#pragma unroll
            for (int j = 0; j < 8; ++j)
                s[j] = (short)bf16r(xp[(size_t)j * (T_ * V_)]);
            *(short8*)&U[col * XB_STRIDE + cg * 8] = s;
        }
        __syncthreads();

        // ---- GEMM1: acc[j][ct] (16x16 tiles), K = 192 = 6*32 ----
        float4v acc[3][7];
        {
            float4v bvec[3];
#pragma unroll
            for (int j = 0; j < 3; ++j)
                bvec[j] = *(const float4v*)(bc + (rt0 + j) * 16 + q * 4);
#pragma unroll
            for (int j = 0; j < 3; ++j)
#pragma unroll
                for (int ct = 0; ct < 7; ++ct) acc[j][ct] = bvec[j];
        }

#pragma unroll
        for (int ct = 0; ct < 7; ++ct) {
            const short* xb = &U[(ct * 16 + l15) * XB_STRIDE + q * 8];
#pragma unroll
            for (int ks = 0; ks < 6; ++ks) {
                short8 bfrag = *(const short8*)(xb + ks * 32);
#pragma unroll
                for (int j = 0; j < 3; ++j)
                    acc[j][ct] = __builtin_amdgcn_mfma_f32_16x16x32_bf16(
                        wfrag[j][ks], bfrag, acc[j][ct], 0, 0, 0);
            }
        }
        __syncthreads();   // XB reads done; union region becomes YB

        // write Y (bf16) into YB[(tl*64+cc)][k*25+v]  (pad cols stay stale-finite)
#pragma unroll
        for (int ct = 0; ct < 7; ++ct) {
            int col = ct * 16 + l15;
            if (col < NCOLS) {
                int tl = col / V_;
                int v  = col - tl * V_;
#pragma unroll
                for (int j = 0; j < 3; ++j) {
                    int obase = (rt0 + j) * 16 + q * 4;
#pragma unroll
                    for (int i = 0; i < 4; ++i) {
                        int o   = obase + i;
                        int row = tl * 64 + (o & 63);
                        int cY  = (o >> 6) * V_ + v;
                        U[row * YB_STRIDE + cY] = (short)bf16r(acc[j][ct][i]);
                    }
                }
            }
        }
        __syncthreads();

        // ---- GEMM2: Out[(t,cc)=256][w pad 32] = Ycat[256][pad96] @ Acat ----
        // b2 fragments are loop-invariant; load from global (L2-hot, 6.6 KB) so
        // A2l LDS staging is gone -> 53248 B LDS -> 3 blocks/CU.
        short8 b2[2][3];
#pragma unroll
        for (int nt = 0; nt < 2; ++nt)
#pragma unroll
            for (int ks = 0; ks < 3; ++ks)
                b2[nt][ks] = *(const short8*)&A2T[(nt * 16 + l15) * YB_STRIDE + ks * 32 + q * 8];

        float4v o2[4][2];
#pragma unroll
        for (int mt = 0; mt < 4; ++mt)
#pragma unroll
            for (int nt = 0; nt < 2; ++nt) o2[mt][nt] = (float4v){0.f, 0.f, 0.f, 0.f};

#pragma unroll
        for (int mt = 0; mt < 4; ++mt) {
            int m = (wv * 4 + mt) * 16 + l15;
            const short* yb = &U[m * YB_STRIDE + q * 8];
#pragma unroll
            for (int ks = 0; ks < 3; ++ks) {
                short8 af = *(const short8*)(yb + ks * 32);
#pragma unroll
                for (int nt = 0; nt < 2; ++nt)
                    o2[mt][nt] = __builtin_amdgcn_mfma_f32_16x16x32_bf16(
                        af, b2[nt][ks], o2[mt][nt], 0, 0, 0);
            }
        }

        // store out[n, cc, t0+tl, w]
#pragma unroll
        for (int mt = 0; mt < 4; ++mt) {
#pragma unroll
            for (int nt = 0; nt < 2; ++nt) {
                int w = nt * 16 + l15;
                if (w < V_) {
#pragma unroll
                    for (int i = 0; i < 4; ++i) {
                        int m  = (wv * 4 + mt) * 16 + q * 4 + i;
                        int cc = m & 63, tl = m >> 6;
                        out[((size_t)(n * COUT_ + cc) * T_ + (t0 + tl)) * V_ + w] = o2[mt][nt][i];
                    }
                }
            }
        }

        // ---- y t-partials from YB: racc[u] += sum_tl y[o, tl, v] ----
#pragma unroll
        for (int u = 0; u < 19; ++u) {
            int idx = tid + u * 256;
            if (u < 18 || idx < NYV) {
                int o = idx / V_, v = idx - (idx / V_) * V_;
                int cc = o & 63, k = o >> 6;
                const short* yp = &U[cc * YB_STRIDE + k * V_ + v];
                float s = 0.f;
#pragma unroll
                for (int tl = 0; tl < TCH; ++tl) {
                    unsigned b = (unsigned short)yp[tl * 64 * YB_STRIDE];
                    s += __uint_as_float(b << 16);
                }
                racc[u] += s;
            }
        }
    }

    // flush per-block partials (coalesced)
    float* pb = part + (size_t)blockIdx.x * NYV;
#pragma unroll
    for (int u = 0; u < 19; ++u) {
        int idx = tid + u * 256;
        if (u < 18 || idx < NYV) pb[idx] = racc[u];
    }
}

// ---------- yred: ysum[n, o, v] = (1/T) * sum_tc part[n*16+tc][o,v] -------------
__global__ __launch_bounds__(256) void yred(const float* __restrict__ part,
                                            float* __restrict__ ysum) {
    int i = blockIdx.x * 256 + threadIdx.x;
    if (i >= N_ * NYV) return;
    int n = i / NYV;
    int r = i - n * NYV;
    const float* p = part + (size_t)n * CPN * NYV + r;
    float s = 0.f;
#pragma unroll
    for (int tc = 0; tc < CPN; ++tc) s += p[tc * NYV];
    ysum[i] = s * (1.0f / T_);
}

// ---------- e2: x1m/x2m -> sem -> graphs; block = (n, 10 j's x 25 v) ------------
__global__ __launch_bounds__(256) void e2_graphs(const float* __restrict__ ysum,
                                                 const float* __restrict__ W1,
                                                 const float* __restrict__ b1,
                                                 const float* __restrict__ W2,
                                                 const float* __restrict__ b2,
                                                 const int* __restrict__ node_type,
                                                 float* __restrict__ out) {
    __shared__ float s1[10][V_];
    __shared__ float sem[10];
    const int tid = threadIdx.x;
    const int n  = blockIdx.x >> 5;
    const int jc = blockIdx.x & 31;
    const int jl = tid / V_;
    const int v  = tid - jl * V_;
    const int j  = jc * 10 + jl;
    float x2 = 0.f;
    if (jl < 10) {
        const float* yb = ysum + (size_t)n * NYV + v;
        const float* w1 = W1 + j * OC_;
        const float* w2 = W2 + j * OC_;
        float a1 = b1[j], a2 = b2[j];
        for (int o = 0; o < OC_; ++o) {
            float yv = yb[o * V_];
            a1 += w1[o] * yv;
            a2 += w2[o] * yv;
        }
        s1[jl][v] = a1;
        x2 = a2;
    }
    __syncthreads();
    if (tid < 10) {
        int s = (jc * 10 + tid) >> 6;   // semantic index = j / 64
        float sum = 0.f, cnt = 0.f;
        for (int vv = 0; vv < V_; ++vv)
            if (node_type[vv] == s) { sum += s1[tid][vv]; cnt += 1.f; }
        sem[tid] = sum / cnt;
    }
    __syncthreads();
    if (jl < 10)
        out[OUT_OFF_G + (size_t)n * (SS_ * COUT_ * V_) + j * V_ + v] = sem[jl] - x2;
}

extern "C" void kernel_launch(void* const* d_in, const int* in_sizes, int n_in,
                              void* d_out, int out_size, void* d_ws, size_t ws_size,
                              hipStream_t stream) {
    const float* x         = (const float*)d_in[0];
    const float* A         = (const float*)d_in[1];
    const int*   node_type = (const int*)d_in[2];
    const float* Wc        = (const float*)d_in[3];
    const float* bc        = (const float*)d_in[4];
    const float* W1        = (const float*)d_in[5];
    const float* b1        = (const float*)d_in[6];
    const float* W2        = (const float*)d_in[7];
    const float* b2        = (const float*)d_in[8];
    float* out = (float*)d_out;

    float* part = (float*)d_ws;                    // 1024*4800 floats = 19.7 MB
    float* ysum = part + (size_t)NBLK * NYV;       // 307200 floats
    short* WcB  = (short*)(ysum + N_ * NYV);       // 36864 shorts
    short* A2T  = WcB + OC_ * CIN_;                // 3328 shorts

    hipLaunchKernelGGL(prep, dim3((OC_ * CIN_ + 255) / 256), dim3(256), 0, stream,
                       Wc, A, WcB, A2T, out);
    hipLaunchKernelGGL(fused_mfma, dim3(NBLK), dim3(256), 0, stream,
                       x, WcB, bc, A2T, out, part);
    hipLaunchKernelGGL(yred, dim3((N_ * NYV + 255) / 256), dim3(256), 0, stream,
                       part, ysum);
    hipLaunchKernelGGL(e2_graphs, dim3(N_ * 32), dim3(256), 0, stream,
                       ysum, W1, b1, W2, b2, node_type, out);
}